// Round 16
// baseline (245.335 us; speedup 1.0000x reference)
//
#include <hip/hip_runtime.h>
#include <hip/hip_bf16.h>
#include <cstdint>
#include <cstddef>

typedef __attribute__((ext_vector_type(4))) float f32x4;
typedef __attribute__((ext_vector_type(8))) short bf16x8;

#define B_    2
#define T_    2048
#define EMB_  2048
#define NQ_   32
#define NKV_  8
#define HEAD_ 64
#define NTOT_ 3072
#define M_    (B_ * T_)     // 4096
#define QBLK_ 64
#define NK_   32            // K=2048 / BK=64

#define MFMA_ __builtin_amdgcn_mfma_f32_16x16x32_bf16

__device__ __forceinline__ unsigned short f2bf(float f) {
  union { float f; unsigned int u; } v; v.f = f;
  unsigned int r = v.u + 0x7fffu + ((v.u >> 16) & 1u);
  return (unsigned short)(r >> 16);
}

__device__ __forceinline__ float bf2f(unsigned short u) {
  union { unsigned int u; float f; } v; v.u = (unsigned int)u << 16; return v.f;
}

__device__ __forceinline__ unsigned int pk_bf16(float lo, float hi) {
  __hip_bfloat162 h = __float22bfloat162_rn(make_float2(lo, hi));
  union { __hip_bfloat162 h; unsigned int u; } c; c.h = h;
  return c.u;
}

// raw v_exp_f32 (2^x) — libm exp2f takes the slow OCML fixup path
__device__ __forceinline__ float ex2(float x) {
  float r;
  asm("v_exp_f32 %0, %1" : "=v"(r) : "v"(x));
  return r;
}

__device__ __forceinline__ void gload_lds16(const void* g, void* l) {
  __builtin_amdgcn_global_load_lds(
      (const __attribute__((address_space(1))) void*)g,
      (__attribute__((address_space(3))) void*)l, 16, 0, 0);
}

#define L2_10000 13.2877123795494f
#define QSCALE_  0.18033688011112043f   // 0.125 * log2(e) -> softmax in exp2

// ---------------- single merged prep kernel ----------------
// Segments by blockIdx.x:
//   [0, 8192)        : x fp32 -> bf16 (float4 per thread)
//   [8192, 18432)    : 4 weight transposes (fp32 [R][C] -> bf16 [C][R])
//   18432            : bias concat
//   [18433, 18689)   : cos/sin table (2048 x 32)
__global__ void prep_all_kernel(const float* __restrict__ x,
                                const float* __restrict__ Wq,
                                const float* __restrict__ Wk,
                                const float* __restrict__ Wv,
                                const float* __restrict__ Wo,
                                const float* __restrict__ bq,
                                const float* __restrict__ bk,
                                const float* __restrict__ bv,
                                unsigned short* __restrict__ xb,
                                unsigned short* __restrict__ WqkvT,
                                unsigned short* __restrict__ WoT,
                                float* __restrict__ bcat,
                                float2* __restrict__ cstab) {
  __shared__ float tile[32][33];
  const int bid = blockIdx.x;
  if (bid < 8192) {                       // x -> bf16
    const int i = bid * 256 + threadIdx.x;   // < 2097152
    float4 v = ((const float4*)x)[i];
    unsigned long long pk =
        (unsigned long long)f2bf(v.x) |
        ((unsigned long long)f2bf(v.y) << 16) |
        ((unsigned long long)f2bf(v.z) << 32) |
        ((unsigned long long)f2bf(v.w) << 48);
    *(unsigned long long*)(xb + (size_t)i * 4) = pk;
    return;
  }
  if (bid < 18432) {                      // weight transposes
    const int wb = bid - 8192;
    const int tx = threadIdx.x & 31, ty = threadIdx.x >> 5;
    const float* src;
    unsigned short* dst;
    int C, local;
    if (wb < 4096)      { src = Wq; dst = WqkvT;                       C = 2048; local = wb; }
    else if (wb < 5120) { src = Wk; dst = WqkvT + (size_t)2048 * 2048; C = 512;  local = wb - 4096; }
    else if (wb < 6144) { src = Wv; dst = WqkvT + (size_t)2560 * 2048; C = 512;  local = wb - 5120; }
    else                { src = Wo; dst = WoT;                         C = 2048; local = wb - 6144; }
    const int tilesx = C >> 5;
    const int c0 = (local % tilesx) * 32, r0 = (local / tilesx) * 32;
#pragma unroll
    for (int k = 0; k < 4; ++k)
      tile[ty + 8 * k][tx] = src[(size_t)(r0 + ty + 8 * k) * C + c0 + tx];
    __syncthreads();
#pragma unroll
    for (int k = 0; k < 4; ++k)
      dst[(size_t)(c0 + ty + 8 * k) * 2048 + r0 + tx] = f2bf(tile[tx][ty + 8 * k]);
    return;
  }
  if (bid == 18432) {                     // bias concat
    const int t0 = threadIdx.x;
#pragma unroll
    for (int k = 0; k < 12; ++k) {
      const int i = k * 256 + t0;
      float v;
      if (i < 2048) v = bq[i];
      else if (i < 2560) v = bk[i - 2048];
      else v = bv[i - 2560];
      bcat[i] = v;
    }
    return;
  }
  {                                       // cos/sin table
    const int idx = (bid - 18433) * 256 + threadIdx.x;   // < 65536
    const int t = idx >> 5, i = idx & 31;
    float invf = exp2f(-(float)i * (L2_10000 / 32.f));
    float ang = (float)t * invf;
    float s, c; sincosf(ang, &s, &c);
    cstab[idx] = make_float2(c, s);
  }
}

// ---------------- QKV GEMM: 128x192 tile, 3-phase, K=2048 ----------------
// Fused epilogue: bias + RoPE(Q,K) + V-relayout written DIRECTLY to
// Qh/Kh/Vt — the rope pass and the QKVlin intermediate are eliminated.
// After the main loop the 80KB staging LDS is dead: stage C-tile there
// (bf16, row stride 194 elems = 97 dwords == 1 mod 32 banks -> conflict-free
// column reads), then each thread handles 24 RoPE pairs (d, d+32) — pairs
// are always intra-tile since 64 | 192.

__launch_bounds__(512, 4)
__global__ void gemm_qkv_3ph(const unsigned short* __restrict__ A,
                             const unsigned short* __restrict__ BT,
                             const float* __restrict__ bias,
                             const float2* __restrict__ cstab,
                             unsigned short* __restrict__ Qh,
                             unsigned short* __restrict__ Kh,
                             unsigned short* __restrict__ Vt) {
  __shared__ unsigned short sh[2 * 20480];   // 80 KiB
  const int tid = threadIdx.x;
  const int lane = tid & 63, l16 = lane & 15, lg = lane >> 4;
  const int wave = tid >> 6, wm = wave >> 2, wn = wave & 3;
  const int bid = blockIdx.x;
  const int sw = (bid & 7) * 64 + (bid >> 3);
  const int mt = sw & 31, nt = sw >> 5;
  const int m0 = mt * 128, n0 = nt * 192;
  const int arow = tid >> 3;
  const int usrc = (tid & 7) ^ (arow & 7);
  const int swz = l16 & 7;
  const int uo0 = (lg ^ swz) << 3;
  const int uo1 = ((4 + lg) ^ swz) << 3;

  f32x4 acc[4][3];
#pragma unroll
  for (int i = 0; i < 4; ++i)
#pragma unroll
    for (int j = 0; j < 3; ++j) acc[i][j] = (f32x4){0.f, 0.f, 0.f, 0.f};

  auto STG = [&](int u) {
    if (u >= 5 * NK_) return;
    const int kt = u / 5, j = u % 5;
    char* bufb = (char*)sh + (kt & 1) * 40960;
    if (j < 2) {
      gload_lds16(A + (size_t)(m0 + j * 64 + arow) * 2048 + kt * 64 + usrc * 8,
                  bufb + j * 8192 + tid * 16);
    } else {
      const int jj = j - 2;
      gload_lds16(BT + (size_t)(n0 + jj * 64 + arow) * 2048 + kt * 64 + usrc * 8,
                  bufb + 16384 + jj * 8192 + tid * 16);
    }
  };

#pragma unroll
  for (int u = 0; u < 7; ++u) STG(u);
  asm volatile("s_waitcnt vmcnt(2)" ::: "memory");
  __builtin_amdgcn_s_barrier();

  for (int t = 0; t < NK_; ++t) {
    const unsigned short* Ab = sh + (t & 1) * 20480;
    const unsigned short* Bb = Ab + 8192;

    bf16x8 af[4][2], bfr[2];
#pragma unroll
    for (int fi = 0; fi < 4; ++fi) {
      const int ro = (fi * 32 + wm * 16 + l16) * 64;
      af[fi][0] = *(const bf16x8*)(Ab + ro + uo0);
      af[fi][1] = *(const bf16x8*)(Ab + ro + uo1);
    }
    {
      const int ro = (wn * 16 + l16) * 64;
      bfr[0] = *(const bf16x8*)(Bb + ro + uo0);
      bfr[1] = *(const bf16x8*)(Bb + ro + uo1);
    }
    STG(7 + 5 * t);  STG(8 + 5 * t);
    __builtin_amdgcn_s_barrier();
    asm volatile("s_waitcnt lgkmcnt(0)" ::: "memory");
    __builtin_amdgcn_sched_barrier(0);
    __builtin_amdgcn_s_setprio(1);
#pragma unroll
    for (int fi = 0; fi < 4; ++fi) {
      acc[fi][0] = MFMA_(af[fi][0], bfr[0], acc[fi][0], 0, 0, 0);
      acc[fi][0] = MFMA_(af[fi][1], bfr[1], acc[fi][0], 0, 0, 0);
    }
    __builtin_amdgcn_s_setprio(0);
    __builtin_amdgcn_s_barrier();

    {
      const int ro = (64 + wn * 16 + l16) * 64;
      bfr[0] = *(const bf16x8*)(Bb + ro + uo0);
      bfr[1] = *(const bf16x8*)(Bb + ro + uo1);
    }
    STG(9 + 5 * t);  STG(10 + 5 * t);
    __builtin_amdgcn_s_barrier();
    asm volatile("s_waitcnt lgkmcnt(0)" ::: "memory");
    __builtin_amdgcn_sched_barrier(0);
    __builtin_amdgcn_s_setprio(1);
#pragma unroll
    for (int fi = 0; fi < 4; ++fi) {
      acc[fi][1] = MFMA_(af[fi][0], bfr[0], acc[fi][1], 0, 0, 0);
      acc[fi][1] = MFMA_(af[fi][1], bfr[1], acc[fi][1], 0, 0, 0);
    }
    __builtin_amdgcn_s_setprio(0);
    __builtin_amdgcn_s_barrier();

    {
      const int ro = (128 + wn * 16 + l16) * 64;
      bfr[0] = *(const bf16x8*)(Bb + ro + uo0);
      bfr[1] = *(const bf16x8*)(Bb + ro + uo1);
    }
    STG(11 + 5 * t);
    __builtin_amdgcn_s_barrier();
    asm volatile("s_waitcnt lgkmcnt(0)" ::: "memory");
    __builtin_amdgcn_sched_barrier(0);
    __builtin_amdgcn_s_setprio(1);
#pragma unroll
    for (int fi = 0; fi < 4; ++fi) {
      acc[fi][2] = MFMA_(af[fi][0], bfr[0], acc[fi][2], 0, 0, 0);
      acc[fi][2] = MFMA_(af[fi][1], bfr[1], acc[fi][2], 0, 0, 0);
    }
    __builtin_amdgcn_s_setprio(0);
    if (t < NK_ - 2)       asm volatile("s_waitcnt vmcnt(2)" ::: "memory");
    else if (t == NK_ - 2) asm volatile("s_waitcnt vmcnt(0)" ::: "memory");
    __builtin_amdgcn_s_barrier();
  }

  // ---- fused epilogue: bias -> C-tile in LDS -> RoPE / V-relayout ----
  {
    unsigned short* Clds = sh;   // 128 rows x stride 194; max idx 24829 < 40960
#pragma unroll
    for (int fj = 0; fj < 3; ++fj) {
      const int col = fj * 64 + wn * 16 + l16;
      const float bv = bias[n0 + col];
#pragma unroll
      for (int fi = 0; fi < 4; ++fi) {
        const int row0 = fi * 32 + wm * 16 + lg * 4;
#pragma unroll
        for (int r = 0; r < 4; ++r)
          Clds[(row0 + r) * 194 + col] = f2bf(acc[fi][fj][r] + bv);
      }
    }
    __syncthreads();
    const int row = tid & 127;
    const int qq  = tid >> 7;                 // 4 threads per row
    const int tg  = m0 + row;                 // global row (b*T + t)
    const int b   = tg >> 11, tt = tg & 2047;
#pragma unroll
    for (int k = 0; k < 24; ++k) {
      const int cidx = qq * 24 + k;           // 0..95 leader cols (d<32)
      const int c  = (cidx >> 5) * 64 + (cidx & 31);
      const int gc = n0 + c;
      const int d  = cidx & 31;               // gc & 63, always < 32
      const float x1 = bf2f(Clds[row * 194 + c]);
      const float x2 = bf2f(Clds[row * 194 + c + 32]);
      if (gc < 2048) {                        // Q: RoPE + QSCALE
        const int h = gc >> 6;
        const float2 cs = cstab[(tt << 5) + d];
        unsigned short* qp = Qh + ((size_t)(b * NQ_ + h) * T_ + tt) * HEAD_ + d;
        qp[0]  = f2bf((x1 * cs.x - x2 * cs.y) * QSCALE_);
        qp[32] = f2bf((x2 * cs.x + x1 * cs.y) * QSCALE_);
      } else if (gc < 2560) {                 // K: RoPE
        const int kh = (gc >> 6) - 32;
        const float2 cs = cstab[(tt << 5) + d];
        unsigned short* kp = Kh + ((size_t)(b * NKV_ + kh) * T_ + tt) * HEAD_ + d;
        kp[0]  = f2bf(x1 * cs.x - x2 * cs.y);
        kp[32] = f2bf(x2 * cs.x + x1 * cs.y);
      } else {                                // V: transposed copy
        const int kh = (gc >> 6) - 40;
        unsigned short* vp = Vt + ((size_t)((b * NKV_ + kh) * 64 + d)) * T_ + tt;
        vp[0]            = f2bf(x1);
        vp[32 * (size_t)T_] = f2bf(x2);
      }
    }
  }
}

// ---------------- out GEMM: 128x256 tile, 2-phase, K=2048 (round-14 proven) ----------------

__launch_bounds__(512, 2)
__global__ void gemm_o_2ph(const unsigned short* __restrict__ A,
                           const unsigned short* __restrict__ BT,
                           const float* __restrict__ bias,
                           float* __restrict__ C) {
  __shared__ unsigned short sh[2 * 24576];   // 96 KiB
  const int tid = threadIdx.x;
  const int lane = tid & 63, l16 = lane & 15, lg = lane >> 4;
  const int wave = tid >> 6, wm = wave >> 2, wn = wave & 3;
  const int bid = blockIdx.x;
  const int sw = (bid & 7) * 32 + (bid >> 3);
  const int mt = sw & 31, nt = sw >> 5;
  const int m0 = mt * 128, n0 = nt * 256;
  const int arow = tid >> 3;
  const int usrc = (tid & 7) ^ (arow & 7);
  const int swz = l16 & 7;
  const int uo0 = (lg ^ swz) << 3;
  const int uo1 = ((4 + lg) ^ swz) << 3;

  f32x4 acc[4][4];
#pragma unroll
  for (int i = 0; i < 4; ++i)
#pragma unroll
    for (int j = 0; j < 4; ++j) acc[i][j] = (f32x4){0.f, 0.f, 0.f, 0.f};

  auto STG = [&](int u) {
    if (u >= 6 * NK_) return;
    const int kt = u / 6, j = u % 6;
    char* bufb = (char*)sh + (kt & 1) * 49152;
    if (j < 2) {
      gload_lds16(A + (size_t)(m0 + j * 64 + arow) * 2048 + kt * 64 + usrc * 8,
                  bufb + j * 8192 + tid * 16);
    } else {
      const int jj = j - 2;
      gload_lds16(BT + (size_t)(n0 + jj * 64 + arow) * 2048 + kt * 64 + usrc * 8,
                  bufb + 16384 + jj * 8192 + tid * 16);
    }
  };

#pragma unroll
  for (int u = 0; u < 9; ++u) STG(u);
  asm volatile("s_waitcnt vmcnt(3)" ::: "memory");
  __builtin_amdgcn_s_barrier();

  for (int t = 0; t < NK_; ++t) {
    const unsigned short* Ab = sh + (t & 1) * 24576;
    const unsigned short* Bb = Ab + 8192;

    bf16x8 af[4][2], bfr[2][2];
#pragma unroll
    for (int fi = 0; fi < 4; ++fi) {
      const int ro = (fi * 32 + wm * 16 + l16) * 64;
      af[fi][0] = *(const bf16x8*)(Ab + ro + uo0);
      af[fi][1] = *(const bf16x8*)(Ab + ro + uo1);
    }
#pragma unroll
    for (int fj = 0; fj < 2; ++fj) {
      const int ro = (fj * 64 + wn * 16 + l16) * 64;
      bfr[fj][0] = *(const bf16x8*)(Bb + ro + uo0);
      bfr[fj][1] = *(const bf16x8*)(Bb + ro + uo1);
    }
    STG(9 + 6 * t);  STG(10 + 6 * t);  STG(11 + 6 * t);
    __builtin_amdgcn_s_barrier();
    asm volatile("s_waitcnt lgkmcnt(0)" ::: "memory");
    __builtin_amdgcn_sched_barrier(0);
    __builtin_amdgcn_s_setprio(1);
#pragma unroll
    for (int fi = 0; fi < 4; ++fi)
#pragma unroll
      for (int fj = 0; fj < 2; ++fj) {
        acc[fi][fj] = MFMA_(af[fi][0], bfr[fj][0], acc[fi][fj], 0, 0, 0);
        acc[fi][fj] = MFMA_(af[fi][1], bfr[fj][1], acc[fi][fj], 0, 0, 0);
      }
    __builtin_amdgcn_s_setprio(0);
    __builtin_amdgcn_s_barrier();

#pragma unroll
    for (int fj = 0; fj < 2; ++fj) {
      const int ro = ((2 + fj) * 64 + wn * 16 + l16) * 64;
      bfr[fj][0] = *(const bf16x8*)(Bb + ro + uo0);
      bfr[fj][1] = *(const bf16x8*)(Bb + ro + uo1);
    }
    STG(12 + 6 * t);  STG(13 + 6 * t);  STG(14 + 6 * t);
    __builtin_amdgcn_s_barrier();
    asm volatile("s_waitcnt lgkmcnt(0)" ::: "memory");
    __builtin_amdgcn_sched_barrier(0);
    __builtin_amdgcn_s_setprio(1);
#pragma unroll
    for (int fi = 0; fi < 4; ++fi)
#pragma unroll
      for (int fj = 0; fj < 2; ++fj) {
        acc[fi][2 + fj] = MFMA_(af[fi][0], bfr[fj][0], acc[fi][2 + fj], 0, 0, 0);
        acc[fi][2 + fj] = MFMA_(af[fi][1], bfr[fj][1], acc[fi][2 + fj], 0, 0, 0);
      }
    __builtin_amdgcn_s_setprio(0);
    if (t < NK_ - 2)       asm volatile("s_waitcnt vmcnt(3)" ::: "memory");
    else if (t == NK_ - 2) asm volatile("s_waitcnt vmcnt(0)" ::: "memory");
    __builtin_amdgcn_s_barrier();
  }

#pragma unroll
  for (int fj = 0; fj < 4; ++fj) {
    const int col = n0 + fj * 64 + wn * 16 + l16;
    const float bv = bias[col];
#pragma unroll
    for (int fi = 0; fi < 4; ++fi) {
      const int row0 = m0 + fi * 32 + wm * 16 + lg * 4;
#pragma unroll
      for (int r = 0; r < 4; ++r)
        C[(size_t)(row0 + r) * EMB_ + col] = acc[fi][fj][r] + bv;
    }
  }
}

// ---------------- flash attention: QBLK=64, 4 blocks/CU (round-14) ----------------

__launch_bounds__(256, 2)
__global__ void flash_attn_kernel(const unsigned short* __restrict__ Qh,
                                  const unsigned short* __restrict__ Kh,
                                  const unsigned short* __restrict__ Vt,
                                  unsigned short* __restrict__ Y) {
  __shared__ unsigned short Klds[2][64 * 64];
  __shared__ unsigned short Vlds[2][64 * 64];
  __shared__ unsigned short Plds[4][16 * 64];
  const int tid = threadIdx.x;
  const int wave = tid >> 6, lane = tid & 63;
  const int l16 = lane & 15, lg = lane >> 4;
  const int h = blockIdx.y, b = blockIdx.z;
  const int kh = h >> 2;

  const size_t kbase = (size_t)(b * NKV_ + kh) * T_ * HEAD_;
  const size_t vbase = (size_t)(b * NKV_ + kh) * HEAD_ * T_;
  const int srow = tid >> 3;
  const int csrc = (tid & 7) ^ (srow & 7);
  unsigned short* pl = Plds[wave];
  const f32x4 zero4 = {0.f, 0.f, 0.f, 0.f};
  const short one_bf = (short)0x3F80;
  const bf16x8 onesv = {one_bf, one_bf, one_bf, one_bf,
                        one_bf, one_bf, one_bf, one_bf};

#define STAGE(bi, kv0) do {                                                         \
    gload_lds16(Kh + kbase + (size_t)((kv0) + srow) * HEAD_ + csrc * 8,             \
                (char*)Klds[bi] + tid * 16);                                        \
    gload_lds16(Kh + kbase + (size_t)((kv0) + srow + 32) * HEAD_ + csrc * 8,        \
                (char*)Klds[bi] + 4096 + tid * 16);                                 \
    gload_lds16(Vt + vbase + (size_t)srow * T_ + (kv0) + csrc * 8,                  \
                (char*)Vlds[bi] + tid * 16);                                        \
    gload_lds16(Vt + vbase + (size_t)(srow + 32) * T_ + (kv0) + csrc * 8,           \
                (char*)Vlds[bi] + 4096 + tid * 16);                                 \
  } while (0)

  for (int seg = 0; seg < 2; ++seg) {
    const int qt = seg ? (31 - (int)blockIdx.x) : (int)blockIdx.x;
    const int q0 = qt * QBLK_;
    const int nt = qt + 1;

    bf16x8 aq0, aq1;
    {
      const unsigned short* qp =
          Qh + ((size_t)(b * NQ_ + h) * T_ + q0 + wave * 16 + l16) * HEAD_;
      aq0 = *(const bf16x8*)(qp + lg * 8);
      aq1 = *(const bf16x8*)(qp + 32 + lg * 8);
    }

    f32x4 oacc[4];
    f32x4 lsum = zero4;
#pragma unroll
    for (int df = 0; df < 4; ++df) oacc[df] = zero4;
    float mreg = -1e30f;

    STAGE(0, 0);

    for (int t = 0; t < nt; ++t) {
      if (t + 1 < nt) {
        STAGE((t + 1) & 1, (t + 1) * 64);
        asm volatile("s_waitcnt vmcnt(8)" ::: "memory");
      } else {
        asm volatile("s_waitcnt vmcnt(0)" ::: "memory");
      }
      __builtin_amdgcn_s_barrier();
      __builtin_amdgcn_sched_barrier(0);

      const unsigned short* Kb = Klds[t & 1];
      const unsigned short* Vb = Vlds[t & 1];
      const int kv0 = t * 64;

      float p[4][4];
#pragma unroll
      for (int cf = 0; cf < 4; ++cf) {
        const int krow = cf * 16 + l16;
        const bf16x8 k0 = *(const bf16x8*)(Kb + krow * 64 + ((lg ^ (krow & 7)) << 3));
        const bf16x8 k1 = *(const bf16x8*)(Kb + krow * 64 + (((4 + lg) ^ (krow & 7)) << 3));
        f32x4 z = zero4;
        z = MFMA_(k0, aq0, z, 0, 0, 0);
        z = MFMA_(k1, aq1, z, 0, 0, 0);
#pragma unroll
        for (int r = 0; r < 4; ++r) p[cf][r] = z[r];
      }

      if (t == nt - 1) {
        const int qg = q0 + wave * 16 + l16;
#pragma unroll
        for (int cf = 0; cf < 4; ++cf)
#pragma unroll
          for (int r = 0; r < 4; ++r)
            if (kv0 + cf * 16 + lg * 4 + r > qg) p[cf][r] = -1e30f;
      }

      float m = mreg;
#pragma unroll
      for (int cf = 0; cf < 4; ++cf) {
        m = fmaxf(m, fmaxf(p[cf][0], p[cf][1]));
        m = fmaxf(m, fmaxf(p[cf][2], p[cf][3]));
      }
      m = fmaxf(m, __shfl_xor(m, 16, 64));
      m = fmaxf(m, __shfl_xor(m, 32, 64));

      if (!__all(m - mreg <= 8.f)) {
        const float corr = ex2(mreg - m);
        mreg = m;
        lsum[0] *= corr;
#pragma unroll
        for (int df = 0; df < 4; ++df)
#pragma unroll
          for (int r = 0; r < 4; ++r) oacc[df][r] *= corr;
      }

#pragma unroll
      for (int cf = 0; cf < 4; ++cf)
#pragma unroll
        for (int r = 0; r < 4; ++r)
          p[cf][r] = ex2(p[cf][r] - mreg);

      const int row = l16;
#pragma unroll
      for (int cf = 0; cf < 4; ++cf) {
        const unsigned int w0 = pk_bf16(p[cf][0], p[cf][1]);
        const unsigned int w1 = pk_bf16(p[cf][2], p[cf][3]);
        const int u = cf * 2 + (lg >> 1);
        char* ad = (char*)pl + row * 128 + ((u ^ (row & 7)) << 4) + ((lg & 1) << 3);
        *(unsigned long long*)ad =
            (unsigned long long)w0 | ((unsigned long long)w1 << 32);
      }
      bf16x8 pf[2];
#pragma unroll
      for (int k2 = 0; k2 < 2; ++k2) {
        const int u = k2 * 4 + lg;
        pf[k2] = *(const bf16x8*)((char*)pl + row * 128 + ((u ^ (row & 7)) << 4));
      }

      lsum = MFMA_(onesv, pf[0], lsum, 0, 0, 0);
      lsum = MFMA_(onesv, pf[1], lsum, 0, 0, 0);
#pragma unroll
      for (int df = 0; df < 4; ++df) {
        const int vrow = df * 16 + l16;
        const bf16x8 v0 = *(const bf16x8*)(Vb + vrow * 64 + ((lg ^ (vrow & 7)) << 3));
        const bf16x8 v1 = *(const bf16x8*)(Vb + vrow * 64 + (((4 + lg) ^ (vrow & 7)) << 3));
        oacc[df] = MFMA_(v0, pf[0], oacc[df], 0, 0, 0);
        oacc[df] = MFMA_(v1, pf[1], oacc[df], 0, 0, 0);
      }

      asm volatile("s_waitcnt lgkmcnt(0)" ::: "memory");
      __builtin_amdgcn_sched_barrier(0);
      __builtin_amdgcn_s_barrier();
    }

    {
      const float inv = 1.f / lsum[0];
      const int tq = q0 + wave * 16 + l16;
      unsigned short* yp = Y + ((size_t)(b * T_ + tq)) * EMB_ + h * HEAD_;
#pragma unroll
      for (int df = 0; df < 4; ++df) {
        const unsigned int w0 = pk_bf16(oacc[df][0] * inv, oacc[df][1] * inv);
        const unsigned int w1 = pk_bf16(oacc[df][2] * inv, oacc[df][3] * inv);
        *(unsigned long long*)(yp + df * 16 + lg * 4) =
            (unsigned long long)w0 | ((unsigned long long)w1 << 32);
      }
    }
  }
#undef STAGE
}

// ---------------- launch ----------------

extern "C" void kernel_launch(void* const* d_in, const int* in_sizes, int n_in,
                              void* d_out, int out_size, void* d_ws, size_t ws_size,
                              hipStream_t stream) {
  const float* x  = (const float*)d_in[0];
  const float* Wq = (const float*)d_in[1];
  const float* bq = (const float*)d_in[2];
  const float* Wk = (const float*)d_in[3];
  const float* bk = (const float*)d_in[4];
  const float* Wv = (const float*)d_in[5];
  const float* bv = (const float*)d_in[6];
  const float* Wo = (const float*)d_in[7];
  const float* bo = (const float*)d_in[8];
  float* out = (float*)d_out;

  char* ws = (char*)d_ws;
  size_t off = 0;
  auto alloc = [&](size_t bytes) {
    void* p = ws + off;
    off += (bytes + 255) & ~(size_t)255;
    return p;
  };
  unsigned short* xb     = (unsigned short*)alloc((size_t)M_ * EMB_ * 2);
  unsigned short* WqkvT  = (unsigned short*)alloc((size_t)NTOT_ * EMB_ * 2);
  unsigned short* WoT    = (unsigned short*)alloc((size_t)EMB_ * EMB_ * 2);
  float*          bcat   = (float*)alloc((size_t)NTOT_ * 4);
  float2*         cstab  = (float2*)alloc((size_t)T_ * 32 * 8);
  unsigned short* Qh     = (unsigned short*)alloc((size_t)B_ * NQ_ * T_ * HEAD_ * 2);
  unsigned short* Kh     = (unsigned short*)alloc((size_t)B_ * NKV_ * T_ * HEAD_ * 2);
  unsigned short* Vt     = (unsigned short*)alloc((size_t)B_ * NKV_ * HEAD_ * T_ * 2);
  unsigned short* Yb     = (unsigned short*)alloc((size_t)M_ * EMB_ * 2);

  // prep: 1 launch (x cvt + weight transposes + bias concat + cos/sin table)
  prep_all_kernel<<<18689, 256, 0, stream>>>(x, Wq, Wk, Wv, Wo, bq, bk, bv,
                                             xb, WqkvT, WoT, bcat, cstab);

  // QKV projection + fused RoPE/V-relayout: writes Qh/Kh/Vt directly
  gemm_qkv_3ph<<<512, 512, 0, stream>>>(xb, WqkvT, bcat, cstab, Qh, Kh, Vt);

  // flash attention: QBLK=64, paired (x, 31-x), 1024 blocks = 4/CU
  flash_attn_kernel<<<dim3(16, NQ_, B_), 256, 0, stream>>>(Qh, Kh, Vt, Yb);

  // output projection: 128x256 2-phase, 256 blocks, fp32 out
  gemm_o_2ph<<<256, 512, 0, stream>>>(Yb, WoT, bo, out);

  (void)in_sizes; (void)n_in; (void)out_size; (void)ws_size;
}

// Round 17
// 193.733 us; speedup vs baseline: 1.2664x; 1.2664x over previous
//
#include <hip/hip_runtime.h>
#include <hip/hip_bf16.h>
#include <cstdint>
#include <cstddef>

typedef __attribute__((ext_vector_type(4))) float f32x4;
typedef __attribute__((ext_vector_type(8))) short bf16x8;

#define B_    2
#define T_    2048
#define EMB_  2048
#define NQ_   32
#define NKV_  8
#define HEAD_ 64
#define NTOT_ 3072
#define M_    (B_ * T_)     // 4096
#define QBLK_ 64
#define NK_   32            // K=2048 / BK=64

#define MFMA_ __builtin_amdgcn_mfma_f32_16x16x32_bf16

__device__ __forceinline__ unsigned short f2bf(float f) {
  union { float f; unsigned int u; } v; v.f = f;
  unsigned int r = v.u + 0x7fffu + ((v.u >> 16) & 1u);
  return (unsigned short)(r >> 16);
}

__device__ __forceinline__ float bf2f(unsigned short u) {
  union { unsigned int u; float f; } v; v.u = (unsigned int)u << 16; return v.f;
}

__device__ __forceinline__ unsigned int pk_bf16(float lo, float hi) {
  __hip_bfloat162 h = __float22bfloat162_rn(make_float2(lo, hi));
  union { __hip_bfloat162 h; unsigned int u; } c; c.h = h;
  return c.u;
}

// raw v_exp_f32 (2^x) — libm exp2f takes the slow OCML fixup path
__device__ __forceinline__ float ex2(float x) {
  float r;
  asm("v_exp_f32 %0, %1" : "=v"(r) : "v"(x));
  return r;
}

__device__ __forceinline__ void gload_lds16(const void* g, void* l) {
  __builtin_amdgcn_global_load_lds(
      (const __attribute__((address_space(1))) void*)g,
      (__attribute__((address_space(3))) void*)l, 16, 0, 0);
}

#define L2_10000 13.2877123795494f
#define QSCALE_  0.18033688011112043f   // 0.125 * log2(e) -> softmax in exp2

// ---------------- single merged prep kernel ----------------
__global__ void prep_all_kernel(const float* __restrict__ x,
                                const float* __restrict__ Wq,
                                const float* __restrict__ Wk,
                                const float* __restrict__ Wv,
                                const float* __restrict__ Wo,
                                const float* __restrict__ bq,
                                const float* __restrict__ bk,
                                const float* __restrict__ bv,
                                unsigned short* __restrict__ xb,
                                unsigned short* __restrict__ WqkvT,
                                unsigned short* __restrict__ WoT,
                                float* __restrict__ bcat,
                                float2* __restrict__ cstab) {
  __shared__ float tile[32][33];
  const int bid = blockIdx.x;
  if (bid < 8192) {                       // x -> bf16
    const int i = bid * 256 + threadIdx.x;   // < 2097152
    float4 v = ((const float4*)x)[i];
    unsigned long long pk =
        (unsigned long long)f2bf(v.x) |
        ((unsigned long long)f2bf(v.y) << 16) |
        ((unsigned long long)f2bf(v.z) << 32) |
        ((unsigned long long)f2bf(v.w) << 48);
    *(unsigned long long*)(xb + (size_t)i * 4) = pk;
    return;
  }
  if (bid < 18432) {                      // weight transposes
    const int wb = bid - 8192;
    const int tx = threadIdx.x & 31, ty = threadIdx.x >> 5;
    const float* src;
    unsigned short* dst;
    int C, local;
    if (wb < 4096)      { src = Wq; dst = WqkvT;                       C = 2048; local = wb; }
    else if (wb < 5120) { src = Wk; dst = WqkvT + (size_t)2048 * 2048; C = 512;  local = wb - 4096; }
    else if (wb < 6144) { src = Wv; dst = WqkvT + (size_t)2560 * 2048; C = 512;  local = wb - 5120; }
    else                { src = Wo; dst = WoT;                         C = 2048; local = wb - 6144; }
    const int tilesx = C >> 5;
    const int c0 = (local % tilesx) * 32, r0 = (local / tilesx) * 32;
#pragma unroll
    for (int k = 0; k < 4; ++k)
      tile[ty + 8 * k][tx] = src[(size_t)(r0 + ty + 8 * k) * C + c0 + tx];
    __syncthreads();
#pragma unroll
    for (int k = 0; k < 4; ++k)
      dst[(size_t)(c0 + ty + 8 * k) * 2048 + r0 + tx] = f2bf(tile[tx][ty + 8 * k]);
    return;
  }
  if (bid == 18432) {                     // bias concat
    const int t0 = threadIdx.x;
#pragma unroll
    for (int k = 0; k < 12; ++k) {
      const int i = k * 256 + t0;
      float v;
      if (i < 2048) v = bq[i];
      else if (i < 2560) v = bk[i - 2048];
      else v = bv[i - 2560];
      bcat[i] = v;
    }
    return;
  }
  {                                       // cos/sin table
    const int idx = (bid - 18433) * 256 + threadIdx.x;   // < 65536
    const int t = idx >> 5, i = idx & 31;
    float invf = exp2f(-(float)i * (L2_10000 / 32.f));
    float ang = (float)t * invf;
    float s, c; sincosf(ang, &s, &c);
    cstab[idx] = make_float2(c, s);
  }
}

// ---------------- QKV GEMM: 128x192 tile, 3-phase + fused RoPE epilogue ----------------
// Fused epilogue v2 (lane-coalesced): C-tile staged in LDS (stride 194:
// conflict-free rows AND columns). Pass A (Q/K): lanes sweep d -> 64B
// contiguous stores. Pass B (V): lanes sweep rows (tt) -> 128B contiguous
// stores into the transposed Vt layout.

__launch_bounds__(512, 4)
__global__ void gemm_qkv_3ph(const unsigned short* __restrict__ A,
                             const unsigned short* __restrict__ BT,
                             const float* __restrict__ bias,
                             const float2* __restrict__ cstab,
                             unsigned short* __restrict__ Qh,
                             unsigned short* __restrict__ Kh,
                             unsigned short* __restrict__ Vt) {
  __shared__ unsigned short sh[2 * 20480];   // 80 KiB
  const int tid = threadIdx.x;
  const int lane = tid & 63, l16 = lane & 15, lg = lane >> 4;
  const int wave = tid >> 6, wm = wave >> 2, wn = wave & 3;
  const int bid = blockIdx.x;
  const int sw = (bid & 7) * 64 + (bid >> 3);
  const int mt = sw & 31, nt = sw >> 5;
  const int m0 = mt * 128, n0 = nt * 192;
  const int arow = tid >> 3;
  const int usrc = (tid & 7) ^ (arow & 7);
  const int swz = l16 & 7;
  const int uo0 = (lg ^ swz) << 3;
  const int uo1 = ((4 + lg) ^ swz) << 3;

  f32x4 acc[4][3];
#pragma unroll
  for (int i = 0; i < 4; ++i)
#pragma unroll
    for (int j = 0; j < 3; ++j) acc[i][j] = (f32x4){0.f, 0.f, 0.f, 0.f};

  auto STG = [&](int u) {
    if (u >= 5 * NK_) return;
    const int kt = u / 5, j = u % 5;
    char* bufb = (char*)sh + (kt & 1) * 40960;
    if (j < 2) {
      gload_lds16(A + (size_t)(m0 + j * 64 + arow) * 2048 + kt * 64 + usrc * 8,
                  bufb + j * 8192 + tid * 16);
    } else {
      const int jj = j - 2;
      gload_lds16(BT + (size_t)(n0 + jj * 64 + arow) * 2048 + kt * 64 + usrc * 8,
                  bufb + 16384 + jj * 8192 + tid * 16);
    }
  };

#pragma unroll
  for (int u = 0; u < 7; ++u) STG(u);
  asm volatile("s_waitcnt vmcnt(2)" ::: "memory");
  __builtin_amdgcn_s_barrier();

  for (int t = 0; t < NK_; ++t) {
    const unsigned short* Ab = sh + (t & 1) * 20480;
    const unsigned short* Bb = Ab + 8192;

    bf16x8 af[4][2], bfr[2];
#pragma unroll
    for (int fi = 0; fi < 4; ++fi) {
      const int ro = (fi * 32 + wm * 16 + l16) * 64;
      af[fi][0] = *(const bf16x8*)(Ab + ro + uo0);
      af[fi][1] = *(const bf16x8*)(Ab + ro + uo1);
    }
    {
      const int ro = (wn * 16 + l16) * 64;
      bfr[0] = *(const bf16x8*)(Bb + ro + uo0);
      bfr[1] = *(const bf16x8*)(Bb + ro + uo1);
    }
    STG(7 + 5 * t);  STG(8 + 5 * t);
    __builtin_amdgcn_s_barrier();
    asm volatile("s_waitcnt lgkmcnt(0)" ::: "memory");
    __builtin_amdgcn_sched_barrier(0);
    __builtin_amdgcn_s_setprio(1);
#pragma unroll
    for (int fi = 0; fi < 4; ++fi) {
      acc[fi][0] = MFMA_(af[fi][0], bfr[0], acc[fi][0], 0, 0, 0);
      acc[fi][0] = MFMA_(af[fi][1], bfr[1], acc[fi][0], 0, 0, 0);
    }
    __builtin_amdgcn_s_setprio(0);
    __builtin_amdgcn_s_barrier();

    {
      const int ro = (64 + wn * 16 + l16) * 64;
      bfr[0] = *(const bf16x8*)(Bb + ro + uo0);
      bfr[1] = *(const bf16x8*)(Bb + ro + uo1);
    }
    STG(9 + 5 * t);  STG(10 + 5 * t);
    __builtin_amdgcn_s_barrier();
    asm volatile("s_waitcnt lgkmcnt(0)" ::: "memory");
    __builtin_amdgcn_sched_barrier(0);
    __builtin_amdgcn_s_setprio(1);
#pragma unroll
    for (int fi = 0; fi < 4; ++fi) {
      acc[fi][1] = MFMA_(af[fi][0], bfr[0], acc[fi][1], 0, 0, 0);
      acc[fi][1] = MFMA_(af[fi][1], bfr[1], acc[fi][1], 0, 0, 0);
    }
    __builtin_amdgcn_s_setprio(0);
    __builtin_amdgcn_s_barrier();

    {
      const int ro = (128 + wn * 16 + l16) * 64;
      bfr[0] = *(const bf16x8*)(Bb + ro + uo0);
      bfr[1] = *(const bf16x8*)(Bb + ro + uo1);
    }
    STG(11 + 5 * t);
    __builtin_amdgcn_s_barrier();
    asm volatile("s_waitcnt lgkmcnt(0)" ::: "memory");
    __builtin_amdgcn_sched_barrier(0);
    __builtin_amdgcn_s_setprio(1);
#pragma unroll
    for (int fi = 0; fi < 4; ++fi) {
      acc[fi][2] = MFMA_(af[fi][0], bfr[0], acc[fi][2], 0, 0, 0);
      acc[fi][2] = MFMA_(af[fi][1], bfr[1], acc[fi][2], 0, 0, 0);
    }
    __builtin_amdgcn_s_setprio(0);
    if (t < NK_ - 2)       asm volatile("s_waitcnt vmcnt(2)" ::: "memory");
    else if (t == NK_ - 2) asm volatile("s_waitcnt vmcnt(0)" ::: "memory");
    __builtin_amdgcn_s_barrier();
  }

  // ---- fused epilogue v2: bias -> C-tile in LDS -> coalesced RoPE/V ----
  {
    unsigned short* Clds = sh;   // 128 rows x stride 194; max idx 24829 < 40960
#pragma unroll
    for (int fj = 0; fj < 3; ++fj) {
      const int col = fj * 64 + wn * 16 + l16;
      const float bv = bias[n0 + col];
#pragma unroll
      for (int fi = 0; fi < 4; ++fi) {
        const int row0 = fi * 32 + wm * 16 + lg * 4;
#pragma unroll
        for (int r = 0; r < 4; ++r)
          Clds[(row0 + r) * 194 + col] = f2bf(acc[fi][fj][r] + bv);
      }
    }
    __syncthreads();

    // Pass A — Q/K (gc < 2560): lanes sweep d -> contiguous 64B stores.
    {
      const int d   = tid & 31;
      const int sub = tid >> 5;              // 0..15
#pragma unroll
      for (int k = 0; k < 24; ++k) {
        const int rb   = sub * 24 + k;       // 0..383
        const int row  = rb & 127;
        const int cblk = rb >> 7;            // 0..2
        const int c  = cblk * 64 + d;
        const int gc = n0 + c;
        if (gc < 2560) {
          const int tg = m0 + row;
          const int b  = tg >> 11, tt = tg & 2047;
          const float x1 = bf2f(Clds[row * 194 + c]);
          const float x2 = bf2f(Clds[row * 194 + c + 32]);
          const float2 cs = cstab[(tt << 5) + d];
          if (gc < 2048) {                   // Q: RoPE + QSCALE
            const int h = gc >> 6;
            unsigned short* qp = Qh + ((size_t)(b * NQ_ + h) * T_ + tt) * HEAD_ + d;
            qp[0]  = f2bf((x1 * cs.x - x2 * cs.y) * QSCALE_);
            qp[32] = f2bf((x2 * cs.x + x1 * cs.y) * QSCALE_);
          } else {                           // K: RoPE
            const int kh = (gc >> 6) - 32;
            unsigned short* kp = Kh + ((size_t)(b * NKV_ + kh) * T_ + tt) * HEAD_ + d;
            kp[0]  = f2bf(x1 * cs.x - x2 * cs.y);
            kp[32] = f2bf(x2 * cs.x + x1 * cs.y);
          }
        }
      }
    }

    // Pass B — V (gc >= 2560): lanes sweep rows (tt) -> contiguous stores.
    {
      const int row = tid & 127;
      const int grp = tid >> 7;              // 0..3
      const int tg  = m0 + row;
      const int b   = tg >> 11, tt = tg & 2047;
#pragma unroll
      for (int k = 0; k < 24; ++k) {
        const int cidx = grp * 24 + k;       // 0..95
        const int cblk = cidx >> 5, d = cidx & 31;
        const int c  = cblk * 64 + d;
        const int gc = n0 + c;
        if (gc >= 2560) {
          const int kh = (gc >> 6) - 40;
          const float x1 = bf2f(Clds[row * 194 + c]);
          const float x2 = bf2f(Clds[row * 194 + c + 32]);
          unsigned short* vp = Vt + ((size_t)((b * NKV_ + kh) * 64 + d)) * T_ + tt;
          vp[0]               = f2bf(x1);
          vp[32 * (size_t)T_] = f2bf(x2);
        }
      }
    }
  }
}

// ---------------- out GEMM: 128x256 tile, 2-phase, K=2048 (round-14 proven) ----------------

__launch_bounds__(512, 2)
__global__ void gemm_o_2ph(const unsigned short* __restrict__ A,
                           const unsigned short* __restrict__ BT,
                           const float* __restrict__ bias,
                           float* __restrict__ C) {
  __shared__ unsigned short sh[2 * 24576];   // 96 KiB
  const int tid = threadIdx.x;
  const int lane = tid & 63, l16 = lane & 15, lg = lane >> 4;
  const int wave = tid >> 6, wm = wave >> 2, wn = wave & 3;
  const int bid = blockIdx.x;
  const int sw = (bid & 7) * 32 + (bid >> 3);
  const int mt = sw & 31, nt = sw >> 5;
  const int m0 = mt * 128, n0 = nt * 256;
  const int arow = tid >> 3;
  const int usrc = (tid & 7) ^ (arow & 7);
  const int swz = l16 & 7;
  const int uo0 = (lg ^ swz) << 3;
  const int uo1 = ((4 + lg) ^ swz) << 3;

  f32x4 acc[4][4];
#pragma unroll
  for (int i = 0; i < 4; ++i)
#pragma unroll
    for (int j = 0; j < 4; ++j) acc[i][j] = (f32x4){0.f, 0.f, 0.f, 0.f};

  auto STG = [&](int u) {
    if (u >= 6 * NK_) return;
    const int kt = u / 6, j = u % 6;
    char* bufb = (char*)sh + (kt & 1) * 49152;
    if (j < 2) {
      gload_lds16(A + (size_t)(m0 + j * 64 + arow) * 2048 + kt * 64 + usrc * 8,
                  bufb + j * 8192 + tid * 16);
    } else {
      const int jj = j - 2;
      gload_lds16(BT + (size_t)(n0 + jj * 64 + arow) * 2048 + kt * 64 + usrc * 8,
                  bufb + 16384 + jj * 8192 + tid * 16);
    }
  };

#pragma unroll
  for (int u = 0; u < 9; ++u) STG(u);
  asm volatile("s_waitcnt vmcnt(3)" ::: "memory");
  __builtin_amdgcn_s_barrier();

  for (int t = 0; t < NK_; ++t) {
    const unsigned short* Ab = sh + (t & 1) * 24576;
    const unsigned short* Bb = Ab + 8192;

    bf16x8 af[4][2], bfr[2][2];
#pragma unroll
    for (int fi = 0; fi < 4; ++fi) {
      const int ro = (fi * 32 + wm * 16 + l16) * 64;
      af[fi][0] = *(const bf16x8*)(Ab + ro + uo0);
      af[fi][1] = *(const bf16x8*)(Ab + ro + uo1);
    }
#pragma unroll
    for (int fj = 0; fj < 2; ++fj) {
      const int ro = (fj * 64 + wn * 16 + l16) * 64;
      bfr[fj][0] = *(const bf16x8*)(Bb + ro + uo0);
      bfr[fj][1] = *(const bf16x8*)(Bb + ro + uo1);
    }
    STG(9 + 6 * t);  STG(10 + 6 * t);  STG(11 + 6 * t);
    __builtin_amdgcn_s_barrier();
    asm volatile("s_waitcnt lgkmcnt(0)" ::: "memory");
    __builtin_amdgcn_sched_barrier(0);
    __builtin_amdgcn_s_setprio(1);
#pragma unroll
    for (int fi = 0; fi < 4; ++fi)
#pragma unroll
      for (int fj = 0; fj < 2; ++fj) {
        acc[fi][fj] = MFMA_(af[fi][0], bfr[fj][0], acc[fi][fj], 0, 0, 0);
        acc[fi][fj] = MFMA_(af[fi][1], bfr[fj][1], acc[fi][fj], 0, 0, 0);
      }
    __builtin_amdgcn_s_setprio(0);
    __builtin_amdgcn_s_barrier();

#pragma unroll
    for (int fj = 0; fj < 2; ++fj) {
      const int ro = ((2 + fj) * 64 + wn * 16 + l16) * 64;
      bfr[fj][0] = *(const bf16x8*)(Bb + ro + uo0);
      bfr[fj][1] = *(const bf16x8*)(Bb + ro + uo1);
    }
    STG(12 + 6 * t);  STG(13 + 6 * t);  STG(14 + 6 * t);
    __builtin_amdgcn_s_barrier();
    asm volatile("s_waitcnt lgkmcnt(0)" ::: "memory");
    __builtin_amdgcn_sched_barrier(0);
    __builtin_amdgcn_s_setprio(1);
#pragma unroll
    for (int fi = 0; fi < 4; ++fi)
#pragma unroll
      for (int fj = 0; fj < 2; ++fj) {
        acc[fi][2 + fj] = MFMA_(af[fi][0], bfr[fj][0], acc[fi][2 + fj], 0, 0, 0);
        acc[fi][2 + fj] = MFMA_(af[fi][1], bfr[fj][1], acc[fi][2 + fj], 0, 0, 0);
      }
    __builtin_amdgcn_s_setprio(0);
    if (t < NK_ - 2)       asm volatile("s_waitcnt vmcnt(3)" ::: "memory");
    else if (t == NK_ - 2) asm volatile("s_waitcnt vmcnt(0)" ::: "memory");
    __builtin_amdgcn_s_barrier();
  }

#pragma unroll
  for (int fj = 0; fj < 4; ++fj) {
    const int col = n0 + fj * 64 + wn * 16 + l16;
    const float bv = bias[col];
#pragma unroll
    for (int fi = 0; fi < 4; ++fi) {
      const int row0 = m0 + fi * 32 + wm * 16 + lg * 4;
#pragma unroll
      for (int r = 0; r < 4; ++r)
        C[(size_t)(row0 + r) * EMB_ + col] = acc[fi][fj][r] + bv;
    }
  }
}

// ---------------- flash attention: QBLK=64, 4 blocks/CU (round-14) ----------------

__launch_bounds__(256, 2)
__global__ void flash_attn_kernel(const unsigned short* __restrict__ Qh,
                                  const unsigned short* __restrict__ Kh,
                                  const unsigned short* __restrict__ Vt,
                                  unsigned short* __restrict__ Y) {
  __shared__ unsigned short Klds[2][64 * 64];
  __shared__ unsigned short Vlds[2][64 * 64];
  __shared__ unsigned short Plds[4][16 * 64];
  const int tid = threadIdx.x;
  const int wave = tid >> 6, lane = tid & 63;
  const int l16 = lane & 15, lg = lane >> 4;
  const int h = blockIdx.y, b = blockIdx.z;
  const int kh = h >> 2;

  const size_t kbase = (size_t)(b * NKV_ + kh) * T_ * HEAD_;
  const size_t vbase = (size_t)(b * NKV_ + kh) * HEAD_ * T_;
  const int srow = tid >> 3;
  const int csrc = (tid & 7) ^ (srow & 7);
  unsigned short* pl = Plds[wave];
  const f32x4 zero4 = {0.f, 0.f, 0.f, 0.f};
  const short one_bf = (short)0x3F80;
  const bf16x8 onesv = {one_bf, one_bf, one_bf, one_bf,
                        one_bf, one_bf, one_bf, one_bf};

#define STAGE(bi, kv0) do {                                                         \
    gload_lds16(Kh + kbase + (size_t)((kv0) + srow) * HEAD_ + csrc * 8,             \
                (char*)Klds[bi] + tid * 16);                                        \
    gload_lds16(Kh + kbase + (size_t)((kv0) + srow + 32) * HEAD_ + csrc * 8,        \
                (char*)Klds[bi] + 4096 + tid * 16);                                 \
    gload_lds16(Vt + vbase + (size_t)srow * T_ + (kv0) + csrc * 8,                  \
                (char*)Vlds[bi] + tid * 16);                                        \
    gload_lds16(Vt + vbase + (size_t)(srow + 32) * T_ + (kv0) + csrc * 8,           \
                (char*)Vlds[bi] + 4096 + tid * 16);                                 \
  } while (0)

  for (int seg = 0; seg < 2; ++seg) {
    const int qt = seg ? (31 - (int)blockIdx.x) : (int)blockIdx.x;
    const int q0 = qt * QBLK_;
    const int nt = qt + 1;

    bf16x8 aq0, aq1;
    {
      const unsigned short* qp =
          Qh + ((size_t)(b * NQ_ + h) * T_ + q0 + wave * 16 + l16) * HEAD_;
      aq0 = *(const bf16x8*)(qp + lg * 8);
      aq1 = *(const bf16x8*)(qp + 32 + lg * 8);
    }

    f32x4 oacc[4];
    f32x4 lsum = zero4;
#pragma unroll
    for (int df = 0; df < 4; ++df) oacc[df] = zero4;
    float mreg = -1e30f;

    STAGE(0, 0);

    for (int t = 0; t < nt; ++t) {
      if (t + 1 < nt) {
        STAGE((t + 1) & 1, (t + 1) * 64);
        asm volatile("s_waitcnt vmcnt(8)" ::: "memory");
      } else {
        asm volatile("s_waitcnt vmcnt(0)" ::: "memory");
      }
      __builtin_amdgcn_s_barrier();
      __builtin_amdgcn_sched_barrier(0);

      const unsigned short* Kb = Klds[t & 1];
      const unsigned short* Vb = Vlds[t & 1];
      const int kv0 = t * 64;

      float p[4][4];
#pragma unroll
      for (int cf = 0; cf < 4; ++cf) {
        const int krow = cf * 16 + l16;
        const bf16x8 k0 = *(const bf16x8*)(Kb + krow * 64 + ((lg ^ (krow & 7)) << 3));
        const bf16x8 k1 = *(const bf16x8*)(Kb + krow * 64 + (((4 + lg) ^ (krow & 7)) << 3));
        f32x4 z = zero4;
        z = MFMA_(k0, aq0, z, 0, 0, 0);
        z = MFMA_(k1, aq1, z, 0, 0, 0);
#pragma unroll
        for (int r = 0; r < 4; ++r) p[cf][r] = z[r];
      }

      if (t == nt - 1) {
        const int qg = q0 + wave * 16 + l16;
#pragma unroll
        for (int cf = 0; cf < 4; ++cf)
#pragma unroll
          for (int r = 0; r < 4; ++r)
            if (kv0 + cf * 16 + lg * 4 + r > qg) p[cf][r] = -1e30f;
      }

      float m = mreg;
#pragma unroll
      for (int cf = 0; cf < 4; ++cf) {
        m = fmaxf(m, fmaxf(p[cf][0], p[cf][1]));
        m = fmaxf(m, fmaxf(p[cf][2], p[cf][3]));
      }
      m = fmaxf(m, __shfl_xor(m, 16, 64));
      m = fmaxf(m, __shfl_xor(m, 32, 64));

      if (!__all(m - mreg <= 8.f)) {
        const float corr = ex2(mreg - m);
        mreg = m;
        lsum[0] *= corr;
#pragma unroll
        for (int df = 0; df < 4; ++df)
#pragma unroll
          for (int r = 0; r < 4; ++r) oacc[df][r] *= corr;
      }

#pragma unroll
      for (int cf = 0; cf < 4; ++cf)
#pragma unroll
        for (int r = 0; r < 4; ++r)
          p[cf][r] = ex2(p[cf][r] - mreg);

      const int row = l16;
#pragma unroll
      for (int cf = 0; cf < 4; ++cf) {
        const unsigned int w0 = pk_bf16(p[cf][0], p[cf][1]);
        const unsigned int w1 = pk_bf16(p[cf][2], p[cf][3]);
        const int u = cf * 2 + (lg >> 1);
        char* ad = (char*)pl + row * 128 + ((u ^ (row & 7)) << 4) + ((lg & 1) << 3);
        *(unsigned long long*)ad =
            (unsigned long long)w0 | ((unsigned long long)w1 << 32);
      }
      bf16x8 pf[2];
#pragma unroll
      for (int k2 = 0; k2 < 2; ++k2) {
        const int u = k2 * 4 + lg;
        pf[k2] = *(const bf16x8*)((char*)pl + row * 128 + ((u ^ (row & 7)) << 4));
      }

      lsum = MFMA_(onesv, pf[0], lsum, 0, 0, 0);
      lsum = MFMA_(onesv, pf[1], lsum, 0, 0, 0);
#pragma unroll
      for (int df = 0; df < 4; ++df) {
        const int vrow = df * 16 + l16;
        const bf16x8 v0 = *(const bf16x8*)(Vb + vrow * 64 + ((lg ^ (vrow & 7)) << 3));
        const bf16x8 v1 = *(const bf16x8*)(Vb + vrow * 64 + (((4 + lg) ^ (vrow & 7)) << 3));
        oacc[df] = MFMA_(v0, pf[0], oacc[df], 0, 0, 0);
        oacc[df] = MFMA_(v1, pf[1], oacc[df], 0, 0, 0);
      }

      asm volatile("s_waitcnt lgkmcnt(0)" ::: "memory");
      __builtin_amdgcn_sched_barrier(0);
      __builtin_amdgcn_s_barrier();
    }

    {
      const float inv = 1.f / lsum[0];
      const int tq = q0 + wave * 16 + l16;
      unsigned short* yp = Y + ((size_t)(b * T_ + tq)) * EMB_ + h * HEAD_;
#pragma unroll
      for (int df = 0; df < 4; ++df) {
        const unsigned int w0 = pk_bf16(oacc[df][0] * inv, oacc[df][1] * inv);
        const unsigned int w1 = pk_bf16(oacc[df][2] * inv, oacc[df][3] * inv);
        *(unsigned long long*)(yp + df * 16 + lg * 4) =
            (unsigned long long)w0 | ((unsigned long long)w1 << 32);
      }
    }
  }
#undef STAGE
}

// ---------------- launch ----------------

extern "C" void kernel_launch(void* const* d_in, const int* in_sizes, int n_in,
                              void* d_out, int out_size, void* d_ws, size_t ws_size,
                              hipStream_t stream) {
  const float* x  = (const float*)d_in[0];
  const float* Wq = (const float*)d_in[1];
  const float* bq = (const float*)d_in[2];
  const float* Wk = (const float*)d_in[3];
  const float* bk = (const float*)d_in[4];
  const float* Wv = (const float*)d_in[5];
  const float* bv = (const float*)d_in[6];
  const float* Wo = (const float*)d_in[7];
  const float* bo = (const float*)d_in[8];
  float* out = (float*)d_out;

  char* ws = (char*)d_ws;
  size_t off = 0;
  auto alloc = [&](size_t bytes) {
    void* p = ws + off;
    off += (bytes + 255) & ~(size_t)255;
    return p;
  };
  unsigned short* xb     = (unsigned short*)alloc((size_t)M_ * EMB_ * 2);
  unsigned short* WqkvT  = (unsigned short*)alloc((size_t)NTOT_ * EMB_ * 2);
  unsigned short* WoT    = (unsigned short*)alloc((size_t)EMB_ * EMB_ * 2);
  float*          bcat   = (float*)alloc((size_t)NTOT_ * 4);
  float2*         cstab  = (float2*)alloc((size_t)T_ * 32 * 8);
  unsigned short* Qh     = (unsigned short*)alloc((size_t)B_ * NQ_ * T_ * HEAD_ * 2);
  unsigned short* Kh     = (unsigned short*)alloc((size_t)B_ * NKV_ * T_ * HEAD_ * 2);
  unsigned short* Vt     = (unsigned short*)alloc((size_t)B_ * NKV_ * HEAD_ * T_ * 2);
  unsigned short* Yb     = (unsigned short*)alloc((size_t)M_ * EMB_ * 2);

  // prep: 1 launch (x cvt + weight transposes + bias concat + cos/sin table)
  prep_all_kernel<<<18689, 256, 0, stream>>>(x, Wq, Wk, Wv, Wo, bq, bk, bv,
                                             xb, WqkvT, WoT, bcat, cstab);

  // QKV projection + fused RoPE/V-relayout (coalesced epilogue v2)
  gemm_qkv_3ph<<<512, 512, 0, stream>>>(xb, WqkvT, bcat, cstab, Qh, Kh, Vt);

  // flash attention: QBLK=64, paired (x, 31-x), 1024 blocks = 4/CU
  flash_attn_kernel<<<dim3(16, NQ_, B_), 256, 0, stream>>>(Qh, Kh, Vt, Yb);

  // output projection: 128x256 2-phase, 256 blocks, fp32 out
  gemm_o_2ph<<<256, 512, 0, stream>>>(Yb, WoT, bo, out);

  (void)in_sizes; (void)n_in; (void)out_size; (void)ws_size;
}

// Round 19
// 193.314 us; speedup vs baseline: 1.2691x; 1.0022x over previous
//
#include <hip/hip_runtime.h>
#include <hip/hip_bf16.h>
#include <cstdint>
#include <cstddef>

typedef __attribute__((ext_vector_type(4))) float f32x4;
typedef __attribute__((ext_vector_type(8))) short bf16x8;

#define B_    2
#define T_    2048
#define EMB_  2048
#define NQ_   32
#define NKV_  8
#define HEAD_ 64
#define NTOT_ 3072
#define M_    (B_ * T_)     // 4096
#define QBLK_ 64
#define NK_   32            // K=2048 / BK=64

#define MFMA_ __builtin_amdgcn_mfma_f32_16x16x32_bf16

__device__ __forceinline__ unsigned short f2bf(float f) {
  union { float f; unsigned int u; } v; v.f = f;
  unsigned int r = v.u + 0x7fffu + ((v.u >> 16) & 1u);
  return (unsigned short)(r >> 16);
}

__device__ __forceinline__ float bf2f(unsigned short u) {
  union { unsigned int u; float f; } v; v.u = (unsigned int)u << 16; return v.f;
}

__device__ __forceinline__ unsigned int pk_bf16(float lo, float hi) {
  __hip_bfloat162 h = __float22bfloat162_rn(make_float2(lo, hi));
  union { __hip_bfloat162 h; unsigned int u; } c; c.h = h;
  return c.u;
}

// raw v_exp_f32 (2^x) — libm exp2f takes the slow OCML fixup path
__device__ __forceinline__ float ex2(float x) {
  float r;
  asm("v_exp_f32 %0, %1" : "=v"(r) : "v"(x));
  return r;
}

__device__ __forceinline__ void gload_lds16(const void* g, void* l) {
  __builtin_amdgcn_global_load_lds(
      (const __attribute__((address_space(1))) void*)g,
      (__attribute__((address_space(3))) void*)l, 16, 0, 0);
}

#define L2_10000 13.2877123795494f
#define QSCALE_  0.18033688011112043f   // 0.125 * log2(e) -> softmax in exp2

// ---------------- single merged prep kernel ----------------
__global__ void prep_all_kernel(const float* __restrict__ x,
                                const float* __restrict__ Wq,
                                const float* __restrict__ Wk,
                                const float* __restrict__ Wv,
                                const float* __restrict__ Wo,
                                const float* __restrict__ bq,
                                const float* __restrict__ bk,
                                const float* __restrict__ bv,
                                unsigned short* __restrict__ xb,
                                unsigned short* __restrict__ WqkvT,
                                unsigned short* __restrict__ WoT,
                                float* __restrict__ bcat,
                                float2* __restrict__ cstab) {
  __shared__ float tile[32][33];
  const int bid = blockIdx.x;
  if (bid < 8192) {                       // x -> bf16
    const int i = bid * 256 + threadIdx.x;   // < 2097152
    float4 v = ((const float4*)x)[i];
    unsigned long long pk =
        (unsigned long long)f2bf(v.x) |
        ((unsigned long long)f2bf(v.y) << 16) |
        ((unsigned long long)f2bf(v.z) << 32) |
        ((unsigned long long)f2bf(v.w) << 48);
    *(unsigned long long*)(xb + (size_t)i * 4) = pk;
    return;
  }
  if (bid < 18432) {                      // weight transposes
    const int wb = bid - 8192;
    const int tx = threadIdx.x & 31, ty = threadIdx.x >> 5;
    const float* src;
    unsigned short* dst;
    int C, local;
    if (wb < 4096)      { src = Wq; dst = WqkvT;                       C = 2048; local = wb; }
    else if (wb < 5120) { src = Wk; dst = WqkvT + (size_t)2048 * 2048; C = 512;  local = wb - 4096; }
    else if (wb < 6144) { src = Wv; dst = WqkvT + (size_t)2560 * 2048; C = 512;  local = wb - 5120; }
    else                { src = Wo; dst = WoT;                         C = 2048; local = wb - 6144; }
    const int tilesx = C >> 5;
    const int c0 = (local % tilesx) * 32, r0 = (local / tilesx) * 32;
#pragma unroll
    for (int k = 0; k < 4; ++k)
      tile[ty + 8 * k][tx] = src[(size_t)(r0 + ty + 8 * k) * C + c0 + tx];
    __syncthreads();
#pragma unroll
    for (int k = 0; k < 4; ++k)
      dst[(size_t)(c0 + ty + 8 * k) * 2048 + r0 + tx] = f2bf(tile[tx][ty + 8 * k]);
    return;
  }
  if (bid == 18432) {                     // bias concat
    const int t0 = threadIdx.x;
#pragma unroll
    for (int k = 0; k < 12; ++k) {
      const int i = k * 256 + t0;
      float v;
      if (i < 2048) v = bq[i];
      else if (i < 2560) v = bk[i - 2048];
      else v = bv[i - 2560];
      bcat[i] = v;
    }
    return;
  }
  {                                       // cos/sin table
    const int idx = (bid - 18433) * 256 + threadIdx.x;   // < 65536
    const int t = idx >> 5, i = idx & 31;
    float invf = exp2f(-(float)i * (L2_10000 / 32.f));
    float ang = (float)t * invf;
    float s, c; sincosf(ang, &s, &c);
    cstab[idx] = make_float2(c, s);
  }
}

// ---------------- QKV GEMM: 128x192 tile, 3-phase + fused RoPE epilogue ----------------
// Fused epilogue v2 (lane-coalesced): C-tile staged in LDS (stride 194:
// conflict-free rows AND columns). Pass A (Q/K): lanes sweep d -> 64B
// contiguous stores. Pass B (V): lanes sweep rows (tt) -> 128B contiguous
// stores into the transposed Vt layout.

__launch_bounds__(512, 4)
__global__ void gemm_qkv_3ph(const unsigned short* __restrict__ A,
                             const unsigned short* __restrict__ BT,
                             const float* __restrict__ bias,
                             const float2* __restrict__ cstab,
                             unsigned short* __restrict__ Qh,
                             unsigned short* __restrict__ Kh,
                             unsigned short* __restrict__ Vt) {
  __shared__ unsigned short sh[2 * 20480];   // 80 KiB
  const int tid = threadIdx.x;
  const int lane = tid & 63, l16 = lane & 15, lg = lane >> 4;
  const int wave = tid >> 6, wm = wave >> 2, wn = wave & 3;
  const int bid = blockIdx.x;
  const int sw = (bid & 7) * 64 + (bid >> 3);
  const int mt = sw & 31, nt = sw >> 5;
  const int m0 = mt * 128, n0 = nt * 192;
  const int arow = tid >> 3;
  const int usrc = (tid & 7) ^ (arow & 7);
  const int swz = l16 & 7;
  const int uo0 = (lg ^ swz) << 3;
  const int uo1 = ((4 + lg) ^ swz) << 3;

  f32x4 acc[4][3];
#pragma unroll
  for (int i = 0; i < 4; ++i)
#pragma unroll
    for (int j = 0; j < 3; ++j) acc[i][j] = (f32x4){0.f, 0.f, 0.f, 0.f};

  auto STG = [&](int u) {
    if (u >= 5 * NK_) return;
    const int kt = u / 5, j = u % 5;
    char* bufb = (char*)sh + (kt & 1) * 40960;
    if (j < 2) {
      gload_lds16(A + (size_t)(m0 + j * 64 + arow) * 2048 + kt * 64 + usrc * 8,
                  bufb + j * 8192 + tid * 16);
    } else {
      const int jj = j - 2;
      gload_lds16(BT + (size_t)(n0 + jj * 64 + arow) * 2048 + kt * 64 + usrc * 8,
                  bufb + 16384 + jj * 8192 + tid * 16);
    }
  };

#pragma unroll
  for (int u = 0; u < 7; ++u) STG(u);
  asm volatile("s_waitcnt vmcnt(2)" ::: "memory");
  __builtin_amdgcn_s_barrier();

  for (int t = 0; t < NK_; ++t) {
    const unsigned short* Ab = sh + (t & 1) * 20480;
    const unsigned short* Bb = Ab + 8192;

    bf16x8 af[4][2], bfr[2];
#pragma unroll
    for (int fi = 0; fi < 4; ++fi) {
      const int ro = (fi * 32 + wm * 16 + l16) * 64;
      af[fi][0] = *(const bf16x8*)(Ab + ro + uo0);
      af[fi][1] = *(const bf16x8*)(Ab + ro + uo1);
    }
    {
      const int ro = (wn * 16 + l16) * 64;
      bfr[0] = *(const bf16x8*)(Bb + ro + uo0);
      bfr[1] = *(const bf16x8*)(Bb + ro + uo1);
    }
    STG(7 + 5 * t);  STG(8 + 5 * t);
    __builtin_amdgcn_s_barrier();
    asm volatile("s_waitcnt lgkmcnt(0)" ::: "memory");
    __builtin_amdgcn_sched_barrier(0);
    __builtin_amdgcn_s_setprio(1);
#pragma unroll
    for (int fi = 0; fi < 4; ++fi) {
      acc[fi][0] = MFMA_(af[fi][0], bfr[0], acc[fi][0], 0, 0, 0);
      acc[fi][0] = MFMA_(af[fi][1], bfr[1], acc[fi][0], 0, 0, 0);
    }
    __builtin_amdgcn_s_setprio(0);
    __builtin_amdgcn_s_barrier();

    {
      const int ro = (64 + wn * 16 + l16) * 64;
      bfr[0] = *(const bf16x8*)(Bb + ro + uo0);
      bfr[1] = *(const bf16x8*)(Bb + ro + uo1);
    }
    STG(9 + 5 * t);  STG(10 + 5 * t);
    __builtin_amdgcn_s_barrier();
    asm volatile("s_waitcnt lgkmcnt(0)" ::: "memory");
    __builtin_amdgcn_sched_barrier(0);
    __builtin_amdgcn_s_setprio(1);
#pragma unroll
    for (int fi = 0; fi < 4; ++fi) {
      acc[fi][1] = MFMA_(af[fi][0], bfr[0], acc[fi][1], 0, 0, 0);
      acc[fi][1] = MFMA_(af[fi][1], bfr[1], acc[fi][1], 0, 0, 0);
    }
    __builtin_amdgcn_s_setprio(0);
    __builtin_amdgcn_s_barrier();

    {
      const int ro = (128 + wn * 16 + l16) * 64;
      bfr[0] = *(const bf16x8*)(Bb + ro + uo0);
      bfr[1] = *(const bf16x8*)(Bb + ro + uo1);
    }
    STG(11 + 5 * t);
    __builtin_amdgcn_s_barrier();
    asm volatile("s_waitcnt lgkmcnt(0)" ::: "memory");
    __builtin_amdgcn_sched_barrier(0);
    __builtin_amdgcn_s_setprio(1);
#pragma unroll
    for (int fi = 0; fi < 4; ++fi) {
      acc[fi][2] = MFMA_(af[fi][0], bfr[0], acc[fi][2], 0, 0, 0);
      acc[fi][2] = MFMA_(af[fi][1], bfr[1], acc[fi][2], 0, 0, 0);
    }
    __builtin_amdgcn_s_setprio(0);
    if (t < NK_ - 2)       asm volatile("s_waitcnt vmcnt(2)" ::: "memory");
    else if (t == NK_ - 2) asm volatile("s_waitcnt vmcnt(0)" ::: "memory");
    __builtin_amdgcn_s_barrier();
  }

  // ---- fused epilogue v2: bias -> C-tile in LDS -> coalesced RoPE/V ----
  {
    unsigned short* Clds = sh;   // 128 rows x stride 194; max idx 24829 < 40960
#pragma unroll
    for (int fj = 0; fj < 3; ++fj) {
      const int col = fj * 64 + wn * 16 + l16;
      const float bv = bias[n0 + col];
#pragma unroll
      for (int fi = 0; fi < 4; ++fi) {
        const int row0 = fi * 32 + wm * 16 + lg * 4;
#pragma unroll
        for (int r = 0; r < 4; ++r)
          Clds[(row0 + r) * 194 + col] = f2bf(acc[fi][fj][r] + bv);
      }
    }
    __syncthreads();

    // Pass A — Q/K (gc < 2560): lanes sweep d -> contiguous 64B stores.
    {
      const int d   = tid & 31;
      const int sub = tid >> 5;              // 0..15
#pragma unroll
      for (int k = 0; k < 24; ++k) {
        const int rb   = sub * 24 + k;       // 0..383
        const int row  = rb & 127;
        const int cblk = rb >> 7;            // 0..2
        const int c  = cblk * 64 + d;
        const int gc = n0 + c;
        if (gc < 2560) {
          const int tg = m0 + row;
          const int b  = tg >> 11, tt = tg & 2047;
          const float x1 = bf2f(Clds[row * 194 + c]);
          const float x2 = bf2f(Clds[row * 194 + c + 32]);
          const float2 cs = cstab[(tt << 5) + d];
          if (gc < 2048) {                   // Q: RoPE + QSCALE
            const int h = gc >> 6;
            unsigned short* qp = Qh + ((size_t)(b * NQ_ + h) * T_ + tt) * HEAD_ + d;
            qp[0]  = f2bf((x1 * cs.x - x2 * cs.y) * QSCALE_);
            qp[32] = f2bf((x2 * cs.x + x1 * cs.y) * QSCALE_);
          } else {                           // K: RoPE
            const int kh = (gc >> 6) - 32;
            unsigned short* kp = Kh + ((size_t)(b * NKV_ + kh) * T_ + tt) * HEAD_ + d;
            kp[0]  = f2bf(x1 * cs.x - x2 * cs.y);
            kp[32] = f2bf(x2 * cs.x + x1 * cs.y);
          }
        }
      }
    }

    // Pass B — V (gc >= 2560): lanes sweep rows (tt) -> contiguous stores.
    {
      const int row = tid & 127;
      const int grp = tid >> 7;              // 0..3
      const int tg  = m0 + row;
      const int b   = tg >> 11, tt = tg & 2047;
#pragma unroll
      for (int k = 0; k < 24; ++k) {
        const int cidx = grp * 24 + k;       // 0..95
        const int cblk = cidx >> 5, d = cidx & 31;
        const int c  = cblk * 64 + d;
        const int gc = n0 + c;
        if (gc >= 2560) {
          const int kh = (gc >> 6) - 40;
          const float x1 = bf2f(Clds[row * 194 + c]);
          const float x2 = bf2f(Clds[row * 194 + c + 32]);
          unsigned short* vp = Vt + ((size_t)((b * NKV_ + kh) * 64 + d)) * T_ + tt;
          vp[0]               = f2bf(x1);
          vp[32 * (size_t)T_] = f2bf(x2);
        }
      }
    }
  }
}

// ---------------- out GEMM: 128x256 tile, 2-phase, K=2048 ----------------

__launch_bounds__(512, 2)
__global__ void gemm_o_2ph(const unsigned short* __restrict__ A,
                           const unsigned short* __restrict__ BT,
                           const float* __restrict__ bias,
                           float* __restrict__ C) {
  __shared__ unsigned short sh[2 * 24576];   // 96 KiB
  const int tid = threadIdx.x;
  const int lane = tid & 63, l16 = lane & 15, lg = lane >> 4;
  const int wave = tid >> 6, wm = wave >> 2, wn = wave & 3;
  const int bid = blockIdx.x;
  const int sw = (bid & 7) * 32 + (bid >> 3);
  const int mt = sw & 31, nt = sw >> 5;
  const int m0 = mt * 128, n0 = nt * 256;
  const int arow = tid >> 3;
  const int usrc = (tid & 7) ^ (arow & 7);
  const int swz = l16 & 7;
  const int uo0 = (lg ^ swz) << 3;
  const int uo1 = ((4 + lg) ^ swz) << 3;

  f32x4 acc[4][4];
#pragma unroll
  for (int i = 0; i < 4; ++i)
#pragma unroll
    for (int j = 0; j < 4; ++j) acc[i][j] = (f32x4){0.f, 0.f, 0.f, 0.f};

  auto STG = [&](int u) {
    if (u >= 6 * NK_) return;
    const int kt = u / 6, j = u % 6;
    char* bufb = (char*)sh + (kt & 1) * 49152;
    if (j < 2) {
      gload_lds16(A + (size_t)(m0 + j * 64 + arow) * 2048 + kt * 64 + usrc * 8,
                  bufb + j * 8192 + tid * 16);
    } else {
      const int jj = j - 2;
      gload_lds16(BT + (size_t)(n0 + jj * 64 + arow) * 2048 + kt * 64 + usrc * 8,
                  bufb + 16384 + jj * 8192 + tid * 16);
    }
  };

#pragma unroll
  for (int u = 0; u < 9; ++u) STG(u);
  asm volatile("s_waitcnt vmcnt(3)" ::: "memory");
  __builtin_amdgcn_s_barrier();

  for (int t = 0; t < NK_; ++t) {
    const unsigned short* Ab = sh + (t & 1) * 24576;
    const unsigned short* Bb = Ab + 8192;

    bf16x8 af[4][2], bfr[2][2];
#pragma unroll
    for (int fi = 0; fi < 4; ++fi) {
      const int ro = (fi * 32 + wm * 16 + l16) * 64;
      af[fi][0] = *(const bf16x8*)(Ab + ro + uo0);
      af[fi][1] = *(const bf16x8*)(Ab + ro + uo1);
    }
#pragma unroll
    for (int fj = 0; fj < 2; ++fj) {
      const int ro = (fj * 64 + wn * 16 + l16) * 64;
      bfr[fj][0] = *(const bf16x8*)(Bb + ro + uo0);
      bfr[fj][1] = *(const bf16x8*)(Bb + ro + uo1);
    }
    STG(9 + 6 * t);  STG(10 + 6 * t);  STG(11 + 6 * t);
    __builtin_amdgcn_s_barrier();
    asm volatile("s_waitcnt lgkmcnt(0)" ::: "memory");
    __builtin_amdgcn_sched_barrier(0);
    __builtin_amdgcn_s_setprio(1);
#pragma unroll
    for (int fi = 0; fi < 4; ++fi)
#pragma unroll
      for (int fj = 0; fj < 2; ++fj) {
        acc[fi][fj] = MFMA_(af[fi][0], bfr[fj][0], acc[fi][fj], 0, 0, 0);
        acc[fi][fj] = MFMA_(af[fi][1], bfr[fj][1], acc[fi][fj], 0, 0, 0);
      }
    __builtin_amdgcn_s_setprio(0);
    __builtin_amdgcn_s_barrier();

#pragma unroll
    for (int fj = 0; fj < 2; ++fj) {
      const int ro = ((2 + fj) * 64 + wn * 16 + l16) * 64;
      bfr[fj][0] = *(const bf16x8*)(Bb + ro + uo0);
      bfr[fj][1] = *(const bf16x8*)(Bb + ro + uo1);
    }
    STG(12 + 6 * t);  STG(13 + 6 * t);  STG(14 + 6 * t);
    __builtin_amdgcn_s_barrier();
    asm volatile("s_waitcnt lgkmcnt(0)" ::: "memory");
    __builtin_amdgcn_sched_barrier(0);
    __builtin_amdgcn_s_setprio(1);
#pragma unroll
    for (int fi = 0; fi < 4; ++fi)
#pragma unroll
      for (int fj = 0; fj < 2; ++fj) {
        acc[fi][2 + fj] = MFMA_(af[fi][0], bfr[fj][0], acc[fi][2 + fj], 0, 0, 0);
        acc[fi][2 + fj] = MFMA_(af[fi][1], bfr[fj][1], acc[fi][2 + fj], 0, 0, 0);
      }
    __builtin_amdgcn_s_setprio(0);
    if (t < NK_ - 2)       asm volatile("s_waitcnt vmcnt(3)" ::: "memory");
    else if (t == NK_ - 2) asm volatile("s_waitcnt vmcnt(0)" ::: "memory");
    __builtin_amdgcn_s_barrier();
  }

#pragma unroll
  for (int fj = 0; fj < 4; ++fj) {
    const int col = n0 + fj * 64 + wn * 16 + l16;
    const float bv = bias[col];
#pragma unroll
    for (int fi = 0; fi < 4; ++fi) {
      const int row0 = m0 + fi * 32 + wm * 16 + lg * 4;
#pragma unroll
      for (int r = 0; r < 4; ++r)
        C[(size_t)(row0 + r) * EMB_ + col] = acc[fi][fj][r] + bv;
    }
  }
}

// ---------------- flash attention: QBLK=64, 4 blocks/CU (round-14/17 proven) ----------------

__launch_bounds__(256, 2)
__global__ void flash_attn_kernel(const unsigned short* __restrict__ Qh,
                                  const unsigned short* __restrict__ Kh,
                                  const unsigned short* __restrict__ Vt,
                                  unsigned short* __restrict__ Y) {
  __shared__ unsigned short Klds[2][64 * 64];
  __shared__ unsigned short Vlds[2][64 * 64];
  __shared__ unsigned short Plds[4][16 * 64];
  const int tid = threadIdx.x;
  const int wave = tid >> 6, lane = tid & 63;
  const int l16 = lane & 15, lg = lane >> 4;
  const int h = blockIdx.y, b = blockIdx.z;
  const int kh = h >> 2;

  const size_t kbase = (size_t)(b * NKV_ + kh) * T_ * HEAD_;
  const size_t vbase = (size_t)(b * NKV_ + kh) * HEAD_ * T_;
  const int srow = tid >> 3;
  const int csrc = (tid & 7) ^ (srow & 7);
  unsigned short* pl = Plds[wave];
  const f32x4 zero4 = {0.f, 0.f, 0.f, 0.f};
  const short one_bf = (short)0x3F80;
  const bf16x8 onesv = {one_bf, one_bf, one_bf, one_bf,
                        one_bf, one_bf, one_bf, one_bf};

#define STAGE(bi, kv0) do {                                                         \
    gload_lds16(Kh + kbase + (size_t)((kv0) + srow) * HEAD_ + csrc * 8,             \
                (char*)Klds[bi] + tid * 16);                                        \
    gload_lds16(Kh + kbase + (size_t)((kv0) + srow + 32) * HEAD_ + csrc * 8,        \
                (char*)Klds[bi] + 4096 + tid * 16);                                 \
    gload_lds16(Vt + vbase + (size_t)srow * T_ + (kv0) + csrc * 8,                  \
                (char*)Vlds[bi] + tid * 16);                                        \
    gload_lds16(Vt + vbase + (size_t)(srow + 32) * T_ + (kv0) + csrc * 8,           \
                (char*)Vlds[bi] + 4096 + tid * 16);                                 \
  } while (0)

  for (int seg = 0; seg < 2; ++seg) {
    const int qt = seg ? (31 - (int)blockIdx.x) : (int)blockIdx.x;
    const int q0 = qt * QBLK_;
    const int nt = qt + 1;

    bf16x8 aq0, aq1;
    {
      const unsigned short* qp =
          Qh + ((size_t)(b * NQ_ + h) * T_ + q0 + wave * 16 + l16) * HEAD_;
      aq0 = *(const bf16x8*)(qp + lg * 8);
      aq1 = *(const bf16x8*)(qp + 32 + lg * 8);
    }

    f32x4 oacc[4];
    f32x4 lsum = zero4;
#pragma unroll
    for (int df = 0; df < 4; ++df) oacc[df] = zero4;
    float mreg = -1e30f;

    STAGE(0, 0);

    for (int t = 0; t < nt; ++t) {
      if (t + 1 < nt) {
        STAGE((t + 1) & 1, (t + 1) * 64);
        asm volatile("s_waitcnt vmcnt(8)" ::: "memory");
      } else {
        asm volatile("s_waitcnt vmcnt(0)" ::: "memory");
      }
      __builtin_amdgcn_s_barrier();
      __builtin_amdgcn_sched_barrier(0);

      const unsigned short* Kb = Klds[t & 1];
      const unsigned short* Vb = Vlds[t & 1];
      const int kv0 = t * 64;

      float p[4][4];
#pragma unroll
      for (int cf = 0; cf < 4; ++cf) {
        const int krow = cf * 16 + l16;
        const bf16x8 k0 = *(const bf16x8*)(Kb + krow * 64 + ((lg ^ (krow & 7)) << 3));
        const bf16x8 k1 = *(const bf16x8*)(Kb + krow * 64 + (((4 + lg) ^ (krow & 7)) << 3));
        f32x4 z = zero4;
        z = MFMA_(k0, aq0, z, 0, 0, 0);
        z = MFMA_(k1, aq1, z, 0, 0, 0);
#pragma unroll
        for (int r = 0; r < 4; ++r) p[cf][r] = z[r];
      }

      if (t == nt - 1) {
        const int qg = q0 + wave * 16 + l16;
#pragma unroll
        for (int cf = 0; cf < 4; ++cf)
#pragma unroll
          for (int r = 0; r < 4; ++r)
            if (kv0 + cf * 16 + lg * 4 + r > qg) p[cf][r] = -1e30f;
      }

      float m = mreg;
#pragma unroll
      for (int cf = 0; cf < 4; ++cf) {
        m = fmaxf(m, fmaxf(p[cf][0], p[cf][1]));
        m = fmaxf(m, fmaxf(p[cf][2], p[cf][3]));
      }
      m = fmaxf(m, __shfl_xor(m, 16, 64));
      m = fmaxf(m, __shfl_xor(m, 32, 64));

      if (!__all(m - mreg <= 8.f)) {
        const float corr = ex2(mreg - m);
        mreg = m;
        lsum[0] *= corr;
#pragma unroll
        for (int df = 0; df < 4; ++df)
#pragma unroll
          for (int r = 0; r < 4; ++r) oacc[df][r] *= corr;
      }

#pragma unroll
      for (int cf = 0; cf < 4; ++cf)
#pragma unroll
        for (int r = 0; r < 4; ++r)
          p[cf][r] = ex2(p[cf][r] - mreg);

      const int row = l16;
#pragma unroll
      for (int cf = 0; cf < 4; ++cf) {
        const unsigned int w0 = pk_bf16(p[cf][0], p[cf][1]);
        const unsigned int w1 = pk_bf16(p[cf][2], p[cf][3]);
        const int u = cf * 2 + (lg >> 1);
        char* ad = (char*)pl + row * 128 + ((u ^ (row & 7)) << 4) + ((lg & 1) << 3);
        *(unsigned long long*)ad =
            (unsigned long long)w0 | ((unsigned long long)w1 << 32);
      }
      bf16x8 pf[2];
#pragma unroll
      for (int k2 = 0; k2 < 2; ++k2) {
        const int u = k2 * 4 + lg;
        pf[k2] = *(const bf16x8*)((char*)pl + row * 128 + ((u ^ (row & 7)) << 4));
      }

      lsum = MFMA_(onesv, pf[0], lsum, 0, 0, 0);
      lsum = MFMA_(onesv, pf[1], lsum, 0, 0, 0);
#pragma unroll
      for (int df = 0; df < 4; ++df) {
        const int vrow = df * 16 + l16;
        const bf16x8 v0 = *(const bf16x8*)(Vb + vrow * 64 + ((lg ^ (vrow & 7)) << 3));
        const bf16x8 v1 = *(const bf16x8*)(Vb + vrow * 64 + (((4 + lg) ^ (vrow & 7)) << 3));
        oacc[df] = MFMA_(v0, pf[0], oacc[df], 0, 0, 0);
        oacc[df] = MFMA_(v1, pf[1], oacc[df], 0, 0, 0);
      }

      asm volatile("s_waitcnt lgkmcnt(0)" ::: "memory");
      __builtin_amdgcn_sched_barrier(0);
      __builtin_amdgcn_s_barrier();
    }

    {
      const float inv = 1.f / lsum[0];
      const int tq = q0 + wave * 16 + l16;
      unsigned short* yp = Y + ((size_t)(b * T_ + tq)) * EMB_ + h * HEAD_;
#pragma unroll
      for (int df = 0; df < 4; ++df) {
        const unsigned int w0 = pk_bf16(oacc[df][0] * inv, oacc[df][1] * inv);
        const unsigned int w1 = pk_bf16(oacc[df][2] * inv, oacc[df][3] * inv);
        *(unsigned long long*)(yp + df * 16 + lg * 4) =
            (unsigned long long)w0 | ((unsigned long long)w1 << 32);
      }
    }
  }
#undef STAGE
}

// ---------------- launch ----------------

extern "C" void kernel_launch(void* const* d_in, const int* in_sizes, int n_in,
                              void* d_out, int out_size, void* d_ws, size_t ws_size,
                              hipStream_t stream) {
  const float* x  = (const float*)d_in[0];
  const float* Wq = (const float*)d_in[1];
  const float* bq = (const float*)d_in[2];
  const float* Wk = (const float*)d_in[3];
  const float* bk = (const float*)d_in[4];
  const float* Wv = (const float*)d_in[5];
  const float* bv = (const float*)d_in[6];
  const float* Wo = (const float*)d_in[7];
  const float* bo = (const float*)d_in[8];
  float* out = (float*)d_out;

  char* ws = (char*)d_ws;
  size_t off = 0;
  auto alloc = [&](size_t bytes) {
    void* p = ws + off;
    off += (bytes + 255) & ~(size_t)255;
    return p;
  };
  unsigned short* xb     = (unsigned short*)alloc((size_t)M_ * EMB_ * 2);
  unsigned short* WqkvT  = (unsigned short*)alloc((size_t)NTOT_ * EMB_ * 2);
  unsigned short* WoT    = (unsigned short*)alloc((size_t)EMB_ * EMB_ * 2);
  float*          bcat   = (float*)alloc((size_t)NTOT_ * 4);
  float2*         cstab  = (float2*)alloc((size_t)T_ * 32 * 8);
  unsigned short* Qh     = (unsigned short*)alloc((size_t)B_ * NQ_ * T_ * HEAD_ * 2);
  unsigned short* Kh     = (unsigned short*)alloc((size_t)B_ * NKV_ * T_ * HEAD_ * 2);
  unsigned short* Vt     = (unsigned short*)alloc((size_t)B_ * NKV_ * HEAD_ * T_ * 2);
  unsigned short* Yb     = (unsigned short*)alloc((size_t)M_ * EMB_ * 2);

  // prep: 1 launch (x cvt + weight transposes + bias concat + cos/sin table)
  prep_all_kernel<<<18689, 256, 0, stream>>>(x, Wq, Wk, Wv, Wo, bq, bk, bv,
                                             xb, WqkvT, WoT, bcat, cstab);

  // QKV projection + fused RoPE/V-relayout (coalesced epilogue v2)
  gemm_qkv_3ph<<<512, 512, 0, stream>>>(xb, WqkvT, bcat, cstab, Qh, Kh, Vt);

  // flash attention: QBLK=64, paired (x, 31-x), 1024 blocks = 4/CU
  flash_attn_kernel<<<dim3(16, NQ_, B_), 256, 0, stream>>>(Qh, Kh, Vt, Yb);

  // output projection: 128x256 2-phase, 256 blocks, fp32 out
  gemm_o_2ph<<<256, 512, 0, stream>>>(Yb, WoT, bo, out);

  (void)in_sizes; (void)n_in; (void)out_size; (void)ws_size;
}